// Round 7
// baseline (225.878 us; speedup 1.0000x reference)
//
#include <hip/hip_runtime.h>
#include <hip/hip_cooperative_groups.h>
#include <stdint.h>

namespace cg = cooperative_groups;

#define B_    16
#define CIN_  128
#define COUT_ 128
#define H_    64
#define W_    64
#define L_    4096
#define KK_   1152
#define PW_   66                 // padded image dim (halo 1 each side)
#define PPIX_ (PW_ * PW_)        // 4356

typedef unsigned short u16;
typedef __bf16 bf16x8 __attribute__((ext_vector_type(8)));
typedef float  floatx4 __attribute__((ext_vector_type(4)));
typedef uint32_t u32x4 __attribute__((ext_vector_type(4)));

typedef const __attribute__((address_space(1))) uint32_t* gptr_t;
typedef __attribute__((address_space(3))) uint32_t*       lptr_t;

__device__ __forceinline__ void async_copy16(const void* g, void* l) {
    // stages 64 lanes x 16 B = 1024 B; LDS dest = wave-uniform base + lane*16
    __builtin_amdgcn_global_load_lds((gptr_t)g, (lptr_t)l, 16, 0, 0);
}

__device__ __forceinline__ u16 f2bf(float f) {
    uint32_t u = __builtin_bit_cast(uint32_t, f);
    uint32_t r = u + 0x7FFFu + ((u >> 16) & 1u);   // round-to-nearest-even
    return (u16)(r >> 16);
}

// ---------------------------------------------------------------------------
// ONE cooperative kernel (256 blocks x 512 thr = 1 block/CU, all co-resident).
// Phase 1 (prep): block (b,lt) transposes its own 4 image rows of x into
//   xTp [B][66][66][CIN] bf16 (reusing W_lds as the transpose tile), computes
//   its 1/256 slice of mb[o][l] and wb2[k][o][c].
// __threadfence + grid.sync()  (device scope -> cross-XCD visibility).
// Phase 2 (GEMM, = R6 body): window-resident all-LDS loop with counted-vmcnt
//   triple-buffered A staging; 18 half-steps; raw s_barrier, no vmcnt(0)
//   drain in-loop; setprio around MFMA cluster.
// Fusing removes a launch gap and makes the whole computation ONE dispatch
// (visible in rocprof top-5 -> decomposes our-work vs harness-fixed time).
// ---------------------------------------------------------------------------
__global__ __launch_bounds__(512, 2)
void lmc_fused_kernel(const float* __restrict__ x,
                      const float* __restrict__ mask, const float* __restrict__ mw,
                      const float* __restrict__ bias, const float* __restrict__ w,
                      u16* __restrict__ xTp, float* __restrict__ mb,
                      u16* __restrict__ wb2, float* __restrict__ out) {
    __shared__ u16 W_lds[396 * 128];      // 101,376 B window [pix][c]; phase-1 tile overlay
    __shared__ u16 A_lds[3][128 * 64];    // 3 x 16,384 B half-tap A [o][c-half], XOR-8

    // XCD-chunked bijective swizzle (256 blocks, 8 XCDs): XCD X gets logical
    // [32X, 32X+32) = 2 whole batches -> per-XCD xTp working set ~2.2 MB.
    const int flat    = blockIdx.x;                  // 0..255
    const int logical = (flat & 7) * 32 + (flat >> 3);
    const int b       = logical >> 4;
    const int lt      = logical & 15;
    const int Y       = lt * 4;                      // first image row of tile
    const int l0      = lt * 256;

    const int tid  = threadIdx.x;
    const int lane = tid & 63;
    const int wv   = tid >> 6;                       // 0..7
    const int wm   = (wv >> 2) * 64;                 // o offset  {0,64}
    const int wn   = (wv & 3) * 64;                  // l offset  {0,64,128,192}
    const int lrow = lane & 15;
    const int quad = lane >> 4;

    // =======================================================================
    // Phase 1a: transpose this block's 4 image rows (y = Y..Y+3) into xTp.
    // Tile overlay on W_lds: [64][136] u16 (136*2 B rows -> 16B-aligned).
    // =======================================================================
    {
        u16* tile = (u16*)W_lds;                     // 17,408 B used
        const uint4 z = {0u, 0u, 0u, 0u};
        for (int r = 0; r < 4; ++r) {
            const int y = Y + r;
            // phase A: read coalesced along xdim, convert, scatter tile[x][c]
            {
                const int c  = tid >> 2;             // 0..127
                const int x0 = (tid & 3) * 16;
                const float* src = x + ((size_t)b * CIN_ + c) * L_ + y * 64 + x0;
                #pragma unroll
                for (int j = 0; j < 16; j += 4) {
                    float4 v = *reinterpret_cast<const float4*>(src + j);
                    tile[(x0 + j + 0) * 136 + c] = f2bf(v.x);
                    tile[(x0 + j + 1) * 136 + c] = f2bf(v.y);
                    tile[(x0 + j + 2) * 136 + c] = f2bf(v.z);
                    tile[(x0 + j + 3) * 136 + c] = f2bf(v.w);
                }
            }
            __syncthreads();
            // phase B: write pixels (y+1, xx+1), coalesced in c
            u16* dstrow = xTp + ((size_t)(b * PW_ + (y + 1)) * PW_) * CIN_;
            {
                const int xx = tid >> 3;             // 0..63
                const int cs = (tid & 7) * 16;
                u16* dst = dstrow + (size_t)(xx + 1) * CIN_ + cs;
                *reinterpret_cast<uint4*>(dst)     = *reinterpret_cast<const uint4*>(&tile[xx * 136 + cs]);
                *reinterpret_cast<uint4*>(dst + 8) = *reinterpret_cast<const uint4*>(&tile[xx * 136 + cs + 8]);
            }
            // x-halo: pixels (y+1, 0) and (y+1, 65)
            if (tid < 32) {
                const int pix = (tid >> 4) ? 65 : 0;
                *reinterpret_cast<uint4*>(dstrow + (size_t)pix * CIN_ + (tid & 15) * 8) = z;
            }
            __syncthreads();                          // tile reused next r
        }
        // y-halo rows 0 / 65 of this batch
        if (lt == 0 || lt == 15) {
            u16* brow = xTp + ((size_t)(b * PW_ + (lt == 0 ? 0 : 65)) * PW_) * CIN_;
            for (int i = tid; i < (PW_ * CIN_) / 8; i += 512)   // 1056 uint4
                reinterpret_cast<uint4*>(brow)[i] = z;
        }
    }

    // =======================================================================
    // Phase 1b: mb[o][l] = bias[o] + sum_k mw[o][k]*mask[k][l]
    // block flat handles o = flat>>1, l-half = (flat&1)*2048; 4 l per thread.
    // =======================================================================
    {
        const int o  = flat >> 1;
        const int l  = (flat & 1) * 2048 + tid * 4;
        float m[9];
        #pragma unroll
        for (int k = 0; k < 9; ++k) m[k] = mw[o * 9 + k];
        const float bs = bias[o];
        float4 s = {bs, bs, bs, bs};
        #pragma unroll
        for (int k = 0; k < 9; ++k) {
            float4 mk = *reinterpret_cast<const float4*>(&mask[k * L_ + l]);
            s.x += m[k] * mk.x;  s.y += m[k] * mk.y;
            s.z += m[k] * mk.z;  s.w += m[k] * mk.w;
        }
        *reinterpret_cast<float4*>(&mb[o * L_ + l]) = s;
    }

    // =======================================================================
    // Phase 1c: wb2[k][o][c] = bf16(weight[o][c][k]) — 576 elems per block
    // =======================================================================
    {
        const int e0 = flat * 576 + tid;
        {
            const int e = e0;
            const int k = e >> 14, rem = e & 16383;
            const int o = rem >> 7, c = rem & 127;
            wb2[e] = f2bf(w[(size_t)o * KK_ + c * 9 + k]);
        }
        if (tid < 64) {
            const int e = e0 + 512;
            const int k = e >> 14, rem = e & 16383;
            const int o = rem >> 7, c = rem & 127;
            wb2[e] = f2bf(w[(size_t)o * KK_ + c * 9 + k]);
        }
    }

    __threadfence();                 // release phase-1 writes (device scope)
    cg::this_grid().sync();          // all xTp/mb/wb2 visible to all blocks

    // =======================================================================
    // Phase 2: GEMM (R6 body)
    // =======================================================================
    const char* wb2_c = (const char*)wb2;
    char* A_c = (char*)A_lds;

    // ---- stage 6x66 pixel window (rows Y..Y+5): 99 x 1 KB instrs ----
    // window pixel p: LDS slot s (16B chunks) holds data chunk s^(p&7);
    // linear LDS dest, swizzle applied on the global source chunk.
    {
        const char* xw = (const char*)xTp + ((size_t)(b * PW_ + Y) * PW_) * 256;
        for (int t = wv; t < 99; t += 8) {
            const int p    = t * 4 + quad;
            const int srcc = lrow ^ (p & 7);
            async_copy16(xw + (size_t)p * 256 + srcc * 16,
                         (char*)W_lds + t * 1024);
        }
    }

    // ---- A staging geometry (g-invariant per-lane source offsets) ----
    // LDS A row o (128 B = 8 chunks): slot s holds source chunk s^(o&7).
    const int ao  = (lane >> 3);                          // row-in-8 group
    const int ach = (lane & 7) ^ (ao & 7);                // source chunk
    const int aoff0 = (8 * wv + ao) * 256 + ach * 16;
    // ---- stage A(0) -> buf 0, A(1) -> buf 1 ----
    async_copy16(wb2_c + aoff0,               A_c + wv * 1024);
    async_copy16(wb2_c + aoff0 + 16384,       A_c + wv * 1024 + 8192);
    async_copy16(wb2_c + 128 + aoff0,         A_c + 16384 + wv * 1024);
    async_copy16(wb2_c + 128 + aoff0 + 16384, A_c + 16384 + wv * 1024 + 8192);

    // ---- per-lane window pixel bases + mask bit-pack (36 bits) ----
    int pix0[4];
    uint64_t bits = 0;
    #pragma unroll
    for (int j = 0; j < 4; ++j) {
        const int ll = wn + j * 16 + lrow;           // block-local l 0..255
        pix0[j] = ((ll >> 6) + 1) * 66 + (ll & 63) + 1;
        const int lg = l0 + ll;
        #pragma unroll
        for (int k = 0; k < 9; ++k)
            if (mask[k * L_ + lg] != 0.0f) bits |= (1ull << (k * 4 + j));
    }

    floatx4 acc[4][4];
    #pragma unroll
    for (int i = 0; i < 4; ++i)
        #pragma unroll
        for (int j = 0; j < 4; ++j)
            acc[i][j] = (floatx4){0.f, 0.f, 0.f, 0.f};

    // window (13 oldest instrs) + A(0) done; A(1) may stay in flight
    asm volatile("s_waitcnt vmcnt(2)" ::: "memory");
    __builtin_amdgcn_s_barrier();
    asm volatile("" ::: "memory");   // no ds_read hoisting above the barrier

    // ---- main loop: 18 half-steps (tap = g>>1, c-half = g&1) ----
    int bufr = 0;   // buffer holding A(g)
    int bufw = 2;   // buffer to receive A(g+2)
    for (int g = 0; g < 18; ++g) {
        const int k = g >> 1;

        // issue A(g+2) (in flight across this step's end barrier)
        if (g < 16) {
            const int gn   = g + 2;
            const int koff = (gn >> 1) * 32768 + (gn & 1) * 128;
            char* dstb = A_c + bufw * 16384;
            async_copy16(wb2_c + koff + aoff0,         dstb + wv * 1024);
            async_copy16(wb2_c + koff + aoff0 + 16384, dstb + wv * 1024 + 8192);
        }

        const int sh = (k / 3 - 1) * 66 + (k % 3) - 1;   // window pixel shift
        uint32_t kp[4];
        #pragma unroll
        for (int j = 0; j < 4; ++j)
            kp[j] = 0u - (uint32_t)((bits >> (k * 4 + j)) & 1ull);

        const u16* Ac = (const u16*)(A_c + bufr * 16384);

        #pragma unroll
        for (int ksl = 0; ksl < 2; ++ksl) {              // 32-c slices within half
            const int ksg = (g & 1) * 2 + ksl;           // global c-chunk quad 0..3
            bf16x8 af[4], bf[4];
            #pragma unroll
            for (int i = 0; i < 4; ++i) {
                const int orow = wm + i * 16 + lrow;
                const int slot = (ksl * 4 + quad) ^ (orow & 7);
                af[i] = *reinterpret_cast<const bf16x8*>(&Ac[orow * 64 + slot * 8]);
            }
            #pragma unroll
            for (int j = 0; j < 4; ++j) {
                const int pix  = pix0[j] + sh;
                const int slot = (ksg * 4 + quad) ^ (pix & 7);
                bf16x8 v = *reinterpret_cast<const bf16x8*>(&W_lds[pix * 128 + slot * 8]);
                u32x4 t = __builtin_bit_cast(u32x4, v);
                t &= kp[j];
                bf[j] = __builtin_bit_cast(bf16x8, t);
            }
            __builtin_amdgcn_s_setprio(1);
            #pragma unroll
            for (int i = 0; i < 4; ++i)
                #pragma unroll
                for (int j = 0; j < 4; ++j)
                    acc[i][j] = __builtin_amdgcn_mfma_f32_16x16x32_bf16(
                        af[i], bf[j], acc[i][j], 0, 0, 0);
            __builtin_amdgcn_s_setprio(0);
        }

        // end of step: prove MY A(g+1) slice landed (issued a full step ago),
        // keep A(g+2) in flight, publish via raw barrier (no vmcnt(0) drain!)
        if (g < 16) {
            asm volatile("s_waitcnt vmcnt(2)" ::: "memory");
            __builtin_amdgcn_s_barrier();
            asm volatile("" ::: "memory");
        } else if (g == 16) {
            asm volatile("s_waitcnt vmcnt(0)" ::: "memory");
            __builtin_amdgcn_s_barrier();
            asm volatile("" ::: "memory");
        }
        bufr = (bufr == 2) ? 0 : bufr + 1;
        bufw = (bufw == 2) ? 0 : bufw + 1;
    }

    // ---- epilogue: C/D layout col = lane&15 (l), row = quad*4 + r (o) ----
    #pragma unroll
    for (int i = 0; i < 4; ++i) {
        #pragma unroll
        for (int j = 0; j < 4; ++j) {
            const int l = l0 + wn + j * 16 + lrow;
            #pragma unroll
            for (int r = 0; r < 4; ++r) {
                const int o = wm + i * 16 + quad * 4 + r;
                out[((size_t)b * COUT_ + o) * L_ + l] = acc[i][j][r] + mb[o * L_ + l];
            }
        }
    }
}

// ---------------------------------------------------------------------------
extern "C" void kernel_launch(void* const* d_in, const int* in_sizes, int n_in,
                              void* d_out, int out_size, void* d_ws, size_t ws_size,
                              hipStream_t stream) {
    const float* x      = (const float*)d_in[0];
    const float* mask   = (const float*)d_in[1];
    const float* weight = (const float*)d_in[2];
    const float* mw     = (const float*)d_in[3];
    const float* bias   = (const float*)d_in[4];
    float* out = (float*)d_out;

    char* ws = (char*)d_ws;
    u16*   xTp = (u16*)ws;                                  // 16*4356*128*2 = 17,842,176 B
    u16*   wb2 = (u16*)(ws + 17842176);                     // 294,912 B  [9][128][128] bf16
    float* mb  = (float*)(ws + 17842176 + 294912);          // 2,097,152 B [128][4096] f32

    void* args[] = {(void*)&x, (void*)&mask, (void*)&mw, (void*)&bias, (void*)&weight,
                    (void*)&xTp, (void*)&mb, (void*)&wb2, (void*)&out};
    hipLaunchCooperativeKernel((const void*)lmc_fused_kernel,
                               dim3(256), dim3(512), args, 0, stream);
}

// Round 9
// 118.480 us; speedup vs baseline: 1.9065x; 1.9065x over previous
//
#include <hip/hip_runtime.h>
#include <stdint.h>

#define B_    16
#define CIN_  128
#define COUT_ 128
#define H_    64
#define W_    64
#define L_    4096
#define KK_   1152

typedef unsigned short u16;
typedef __bf16 bf16x8 __attribute__((ext_vector_type(8)));
typedef float  floatx4 __attribute__((ext_vector_type(4)));
typedef uint32_t u32x4 __attribute__((ext_vector_type(4)));

typedef const __attribute__((address_space(1))) uint32_t* gptr_t;
typedef __attribute__((address_space(3))) uint32_t*       lptr_t;

__device__ __forceinline__ void async_copy16(const void* g, void* l) {
    // stages 64 lanes x 16 B = 1024 B; LDS dest = wave-uniform base + lane*16
    __builtin_amdgcn_global_load_lds((gptr_t)g, (lptr_t)l, 16, 0, 0);
}

__device__ __forceinline__ u16 f2bf(float f) {
    uint32_t u = __builtin_bit_cast(uint32_t, f);
    uint32_t r = u + 0x7FFFu + ((u >> 16) & 1u);   // round-to-nearest-even
    return (u16)(r >> 16);
}

// ---------------------------------------------------------------------------
// Small prep (xTp transpose DELETED — now done in-block by the GEMM):
//   blocks 0..127  -> mb[o][l] = bias[o] + sum_k mw[o][k]*mask[k][l]
//   blocks 128..191 -> wb2[k][o][c] = bf16(weight[o][c][k])
// ---------------------------------------------------------------------------
__global__ void lmc_prep_kernel(const float* __restrict__ mask, const float* __restrict__ mw,
                                const float* __restrict__ bias, const float* __restrict__ w,
                                float* __restrict__ mb, u16* __restrict__ wb2) {
    const int bid = blockIdx.x, tid = threadIdx.x;
    if (bid < 128) {
        const int o = bid;
        float m[9];
        #pragma unroll
        for (int k = 0; k < 9; ++k) m[k] = mw[o * 9 + k];
        const float bs = bias[o];
        for (int l = tid; l < L_; l += 256) {
            float s = bs;
            #pragma unroll
            for (int k = 0; k < 9; ++k) s += m[k] * mask[k * L_ + l];
            mb[o * L_ + l] = s;
        }
    } else {
        const int base = (bid - 128) * 2304;
        #pragma unroll
        for (int i = 0; i < 9; ++i) {
            const int e = base + i * 256 + tid;        // 0..147455 exact
            const int k = e >> 14;                     // /16384
            const int rem = e & 16383;
            const int o = rem >> 7, c = rem & 127;
            wb2[e] = f2bf(w[(size_t)o * KK_ + c * 9 + k]);
        }
    }
}

// ---------------------------------------------------------------------------
// Main GEMM with IN-BLOCK transpose (xTp intermediate eliminated).
// Block = 128(o) x 256(l) = 4 image rows. Phase T builds the 6x66x128 bf16
// window in LDS directly from x (f32 NCHW): per wave, 4 coalesced float4
// loads spanning 4 c-rows -> f2bf -> pack 4 c's -> ds_write_b64 into the
// XOR-8 chunk-swizzled layout the main loop reads (slot s of pixel p holds
// data chunk s^(p&7)). Out-of-range rows/cols written as zeros (halo).
// Then the R6 loop: A (wb2) triple-buffered LDS staging at half-tap
// granularity, counted vmcnt(2) (never 0 in-loop), raw s_barrier, setprio.
// 256 blocks x 512 thr = 1 block/CU, LDS 150,528 B; XCD-chunked swizzle
// keeps each XCD on 2 whole batches (x reuse between neighbor tiles in L2).
// Mask applied as bitwise AND on B-fragments (mask is binary -> exact).
// ---------------------------------------------------------------------------
__global__ __launch_bounds__(512, 2)
void lmc_gemm_kernel(const float* __restrict__ x, const u16* __restrict__ wb2,
                     const float* __restrict__ mask, const float* __restrict__ mb,
                     float* __restrict__ out) {
    __shared__ u16 W_lds[396 * 128];      // 101,376 B window [pix][c], XOR-8 chunk swizzle
    __shared__ u16 A_lds[3][128 * 64];    // 3 x 16,384 B half-tap A [o][c-half], XOR-8

    const int flat    = blockIdx.x;                  // 0..255
    const int logical = (flat & 7) * 32 + (flat >> 3);
    const int b       = logical >> 4;
    const int lt      = logical & 15;
    const int Y       = lt * 4;                      // first image row of tile
    const int l0      = lt * 256;

    const int tid  = threadIdx.x;
    const int lane = tid & 63;
    const int wv   = tid >> 6;                       // 0..7
    const int wm   = (wv >> 2) * 64;                 // o offset  {0,64}
    const int wn   = (wv & 3) * 64;                  // l offset  {0,64,128,192}
    const int lrow = lane & 15;
    const int quad = lane >> 4;

    // =======================================================================
    // Phase T: build window (image rows Y-1 .. Y+4) from x, swizzled.
    // =======================================================================
    // x-halo pixels (wx=0 and wx=65, all 6 wy): 12 px * 256 B = 192 uint4
    if (tid < 192) {
        const int h  = tid >> 4;                     // 0..11
        const int px = (h >> 1) * 66 + ((h & 1) ? 65 : 0);
        const uint4 z = {0u, 0u, 0u, 0u};
        *reinterpret_cast<uint4*>((char*)W_lds + px * 256 + (tid & 15) * 16) = z;
    }
    // interior columns (x 0..63 -> wx 1..64); y out of range -> zeros
    {
        const int cg  = lane >> 4;                   // 0..3  (c-quad within 16)
        const int x0  = (lane & 15) * 4;
        const int cb  = wv;                          // this wave's c-block of 16
        const int cbase = cb * 16 + cg * 4;
        const int d     = cb * 2 + (cg >> 1);        // data chunk index (c>>3)
        const int half8 = (cg & 1) * 8;              // byte offset within chunk
        const float* xc = x + ((size_t)(b * CIN_ + cbase) * L_) + x0;

        #pragma unroll
        for (int wy = 0; wy < 6; ++wy) {
            const int y   = Y - 1 + wy;
            const int px0 = wy * 66 + x0 + 1;
            if (y >= 0 && y <= 63) {
                const float* xr = xc + y * 64;
                float4 v0 = *reinterpret_cast<const float4*>(xr);
                float4 v1 = *reinterpret_cast<const float4*>(xr + L_);
                float4 v2 = *reinterpret_cast<const float4*>(xr + 2 * L_);
                float4 v3 = *reinterpret_cast<const float4*>(xr + 3 * L_);
                const float* p0 = (const float*)&v0;
                const float* p1 = (const float*)&v1;
                const float* p2 = (const float*)&v2;
                const float* p3 = (const float*)&v3;
                #pragma unroll
                for (int j = 0; j < 4; ++j) {
                    const int px   = px0 + j;
                    const int slot = d ^ (px & 7);
                    uint2 pk;
                    pk.x = (uint32_t)f2bf(p0[j]) | ((uint32_t)f2bf(p1[j]) << 16);
                    pk.y = (uint32_t)f2bf(p2[j]) | ((uint32_t)f2bf(p3[j]) << 16);
                    *reinterpret_cast<uint2*>((char*)W_lds + px * 256 + slot * 16 + half8) = pk;
                }
            } else {
                const uint2 z2 = {0u, 0u};
                #pragma unroll
                for (int j = 0; j < 4; ++j) {
                    const int px   = px0 + j;
                    const int slot = d ^ (px & 7);
                    *reinterpret_cast<uint2*>((char*)W_lds + px * 256 + slot * 16 + half8) = z2;
                }
            }
        }
    }

    // ---- per-lane window pixel bases + mask bit-pack (36 bits) ----
    int pix0[4];
    uint64_t bits = 0;
    #pragma unroll
    for (int j = 0; j < 4; ++j) {
        const int ll = wn + j * 16 + lrow;           // block-local l 0..255
        pix0[j] = ((ll >> 6) + 1) * 66 + (ll & 63) + 1;
        const int lg = l0 + ll;
        #pragma unroll
        for (int k = 0; k < 9; ++k)
            if (mask[k * L_ + lg] != 0.0f) bits |= (1ull << (k * 4 + j));
    }

    // ---- A staging geometry (g-invariant per-lane source offsets) ----
    // LDS A row o (128 B = 8 chunks): slot s holds source chunk s^(o&7).
    const char* wb2_c = (const char*)wb2;
    char* A_c = (char*)A_lds;
    const int ao  = (lane >> 3);                          // row-in-8 group
    const int ach = (lane & 7) ^ (ao & 7);                // source chunk
    const int aoff0 = (8 * wv + ao) * 256 + ach * 16;
    // ---- stage A(0) -> buf 0, A(1) -> buf 1 (issued LAST: counted wait) ----
    async_copy16(wb2_c + aoff0,               A_c + wv * 1024);
    async_copy16(wb2_c + aoff0 + 16384,       A_c + wv * 1024 + 8192);
    async_copy16(wb2_c + 128 + aoff0,         A_c + 16384 + wv * 1024);
    async_copy16(wb2_c + 128 + aoff0 + 16384, A_c + 16384 + wv * 1024 + 8192);

    floatx4 acc[4][4];
    #pragma unroll
    for (int i = 0; i < 4; ++i)
        #pragma unroll
        for (int j = 0; j < 4; ++j)
            acc[i][j] = (floatx4){0.f, 0.f, 0.f, 0.f};

    // transpose ds_writes visible (lgkmcnt 0); A(0) done, A(1) may fly
    asm volatile("s_waitcnt vmcnt(2) lgkmcnt(0)" ::: "memory");
    __builtin_amdgcn_s_barrier();
    asm volatile("" ::: "memory");   // no ds_read hoisting above the barrier

    // ---- main loop: 18 half-steps (tap = g>>1, c-half = g&1) ----
    int bufr = 0;   // buffer holding A(g)
    int bufw = 2;   // buffer to receive A(g+2)
    for (int g = 0; g < 18; ++g) {
        const int k = g >> 1;

        // issue A(g+2) (in flight across this step's end barrier)
        if (g < 16) {
            const int gn   = g + 2;
            const int koff = (gn >> 1) * 32768 + (gn & 1) * 128;
            char* dstb = A_c + bufw * 16384;
            async_copy16(wb2_c + koff + aoff0,         dstb + wv * 1024);
            async_copy16(wb2_c + koff + aoff0 + 16384, dstb + wv * 1024 + 8192);
        }

        const int sh = (k / 3 - 1) * 66 + (k % 3) - 1;   // window pixel shift
        uint32_t kp[4];
        #pragma unroll
        for (int j = 0; j < 4; ++j)
            kp[j] = 0u - (uint32_t)((bits >> (k * 4 + j)) & 1ull);

        const u16* Ac = (const u16*)(A_c + bufr * 16384);

        #pragma unroll
        for (int ksl = 0; ksl < 2; ++ksl) {              // 32-c slices within half
            const int ksg = (g & 1) * 2 + ksl;           // global c-chunk quad 0..3
            bf16x8 af[4], bf[4];
            #pragma unroll
            for (int i = 0; i < 4; ++i) {
                const int orow = wm + i * 16 + lrow;
                const int slot = (ksl * 4 + quad) ^ (orow & 7);
                af[i] = *reinterpret_cast<const bf16x8*>(&Ac[orow * 64 + slot * 8]);
            }
            #pragma unroll
            for (int j = 0; j < 4; ++j) {
                const int pix  = pix0[j] + sh;
                const int slot = (ksg * 4 + quad) ^ (pix & 7);
                bf16x8 v = *reinterpret_cast<const bf16x8*>(&W_lds[pix * 128 + slot * 8]);
                u32x4 t = __builtin_bit_cast(u32x4, v);
                t &= kp[j];
                bf[j] = __builtin_bit_cast(bf16x8, t);
            }
            __builtin_amdgcn_s_setprio(1);
            #pragma unroll
            for (int i = 0; i < 4; ++i)
                #pragma unroll
                for (int j = 0; j < 4; ++j)
                    acc[i][j] = __builtin_amdgcn_mfma_f32_16x16x32_bf16(
                        af[i], bf[j], acc[i][j], 0, 0, 0);
            __builtin_amdgcn_s_setprio(0);
        }

        // end of step: A(g+1) provably landed (vmcnt(2) leaves only A(g+2)
        // in flight); publish via raw barrier — no vmcnt(0) drain in-loop
        if (g < 16) {
            asm volatile("s_waitcnt vmcnt(2)" ::: "memory");
            __builtin_amdgcn_s_barrier();
            asm volatile("" ::: "memory");
        } else if (g == 16) {
            asm volatile("s_waitcnt vmcnt(0)" ::: "memory");
            __builtin_amdgcn_s_barrier();
            asm volatile("" ::: "memory");
        }
        bufr = (bufr == 2) ? 0 : bufr + 1;
        bufw = (bufw == 2) ? 0 : bufw + 1;
    }

    // ---- epilogue: C/D layout col = lane&15 (l), row = quad*4 + r (o) ----
    #pragma unroll
    for (int i = 0; i < 4; ++i) {
        #pragma unroll
        for (int j = 0; j < 4; ++j) {
            const int l = l0 + wn + j * 16 + lrow;
            #pragma unroll
            for (int r = 0; r < 4; ++r) {
                const int o = wm + i * 16 + quad * 4 + r;
                out[((size_t)b * COUT_ + o) * L_ + l] = acc[i][j][r] + mb[o * L_ + l];
            }
        }
    }
}

// ---------------------------------------------------------------------------
extern "C" void kernel_launch(void* const* d_in, const int* in_sizes, int n_in,
                              void* d_out, int out_size, void* d_ws, size_t ws_size,
                              hipStream_t stream) {
    const float* x      = (const float*)d_in[0];
    const float* mask   = (const float*)d_in[1];
    const float* weight = (const float*)d_in[2];
    const float* mw     = (const float*)d_in[3];
    const float* bias   = (const float*)d_in[4];
    float* out = (float*)d_out;

    char* ws = (char*)d_ws;
    u16*   wb2 = (u16*)ws;                      // 294,912 B  [9][128][128] bf16
    float* mb  = (float*)(ws + 294912);         // 2,097,152 B [128][4096] f32

    lmc_prep_kernel<<<192, 256, 0, stream>>>(mask, mw, bias, weight, mb, wb2);
    lmc_gemm_kernel<<<256, 512, 0, stream>>>(x, wb2, mask, mb, out);
}